// Round 4
// baseline (128.652 us; speedup 1.0000x reference)
//
#include <hip/hip_runtime.h>

#define NUM_MOL 1024
#define KEHALF 7.199822675975274f
#define RCUT 10.0f
// u8 z-table capacity in LDS; + 256-float LUT = 128 KiB static LDS
#define ZS_CAP 130048

__device__ __forceinline__ float softplus_f(float x) {
    // log1p(exp(x)); fast path (params are O(1), tolerance allows ~1e-7 rel)
    return (x > 20.0f) ? x : __logf(1.0f + __expf(x));
}

__device__ __forceinline__ float uni(float x) {
    // force uniform value into an SGPR (frees VGPRs, marks uniformity)
    return __int_as_float(__builtin_amdgcn_readfirstlane(__float_as_int(x)));
}

// ===========================================================================
// Primary path (single kernel, no workspace):
//   - Z is integer-valued in [1,94]: u8 z per atom in LDS (100 KB),
//     z^softplus(apow) via 256-entry LDS LUT. Edge lookups = DS pipe only.
//   - exact early-out: exp underflows to 0 for ~99% of edges; survivors
//     lazily gather idx_m[i] (masked load) and atomicAdd into y[mol]
//     directly. ~30K device atomics over 1024 bins — negligible.
// ===========================================================================

struct SmemT {
    float zptab[256];          // z^softplus(apow), z in [0,255]
    unsigned char zs[ZS_CAP];  // per-atom z
};

__global__ __launch_bounds__(1024, 4) void zbl_edge_lds(
    const float4* __restrict__ r4,
    const int4* __restrict__ idx_i4,
    const int4* __restrict__ idx_j4,
    const int* __restrict__ idx_i,
    const int* __restrict__ idx_j,
    const float* __restrict__ r_ij,
    const float* __restrict__ Z,
    const int* __restrict__ idx_m,
    const float* __restrict__ adiv,
    const float* __restrict__ apow,
    const float* __restrict__ a_vector,
    const float* __restrict__ c_vector,
    float* __restrict__ y, int N, int E)
{
    __shared__ SmemT sm;
    const int tid = threadIdx.x;

    // ---- fill LDS z-table from Z (coalesced float4 reads, u8 packs) ----
    {
        const int nv4 = N >> 2;
        const float4* Z4 = (const float4*)Z;
        uchar4* dst = (uchar4*)sm.zs;
        for (int k = tid; k < nv4; k += blockDim.x) {
            const float4 zv = Z4[k];
            uchar4 pk;
            pk.x = (unsigned char)(int)zv.x;
            pk.y = (unsigned char)(int)zv.y;
            pk.z = (unsigned char)(int)zv.z;
            pk.w = (unsigned char)(int)zv.w;
            dst[k] = pk;
        }
        for (int k = (nv4 << 2) + tid; k < N; k += blockDim.x)
            sm.zs[k] = (unsigned char)(int)Z[k];
        if (tid < 256) {
            const float p = softplus_f(apow[0]);
            sm.zptab[tid] = (tid > 0) ? __powf((float)tid, p) : 0.0f;
        }
    }

    // ---- uniform scalar parameters -> SGPRs ----
    const float sp_adiv = uni(softplus_f(adiv[0]));
    const float sa0 = uni(softplus_f(a_vector[0]));
    const float sa1 = uni(softplus_f(a_vector[1]));
    const float sa2 = uni(softplus_f(a_vector[2]));
    const float sa3 = uni(softplus_f(a_vector[3]));
    float c0 = softplus_f(c_vector[0]);
    float c1 = softplus_f(c_vector[1]);
    float c2 = softplus_f(c_vector[2]);
    float c3 = softplus_f(c_vector[3]);
    const float cinv = 1.0f / (fabsf(c0) + fabsf(c1) + fabsf(c2) + fabsf(c3));
    const float k0 = uni(c0 * cinv);
    const float k1 = uni(c1 * cinv);
    const float k2 = uni(c2 * cinv);
    const float k3 = uni(c3 * cinv);
    const float samin = uni(fminf(fminf(sa0, sa1), fminf(sa2, sa3)));

    __syncthreads();

    auto edge1 = [&](int i, int j, float d2) {
        const int zi = sm.zs[i];                 // ds_read_u8 (random, cheap)
        const int zj = sm.zs[j];
        const float zpi = sm.zptab[zi];          // ds_read_b32 (256-word LUT)
        const float zpj = sm.zptab[zj];
        const float rinv = rsqrtf(d2);
        const float d = d2 * rinv;
        const float ad = (zpi + zpj) * sp_adiv * d;
        // exact early-out: if samin*ad >= 104, every expf flushes to 0.0f
        // -> ft == 0 -> ee == 0 (bit-identical to full evaluation).
        // Survivors (~1%): masked idx_m gather + direct global atomic.
        if (ad * samin < 104.0f) {
            const float u = d * (1.0f / RCUT);
            const float u3 = u * u * u;
            float fc = 1.0f + u3 * (-10.0f + u * (15.0f - 6.0f * u));
            fc = (d < RCUT) ? fc : 0.0f;
            const float ft = k0 * __expf(-sa0 * ad) + k1 * __expf(-sa1 * ad)
                           + k2 * __expf(-sa2 * ad) + k3 * __expf(-sa3 * ad);
            const float ee = KEHALF * ft * fc * (float)(zi * zj) * rinv;
            if (ee != 0.0f) atomicAdd(&y[idx_m[i]], ee);
        }
    };
    auto edge4 = [&](const int4& vi, const int4& vj,
                     const float4& r0, const float4& r1, const float4& r2) {
        edge1(vi.x, vj.x, r0.x * r0.x + r0.y * r0.y + r0.z * r0.z);
        edge1(vi.y, vj.y, r0.w * r0.w + r1.x * r1.x + r1.y * r1.y);
        edge1(vi.z, vj.z, r1.z * r1.z + r1.w * r1.w + r2.x * r2.x);
        edge1(vi.w, vj.w, r2.y * r2.y + r2.z * r2.z + r2.w * r2.w);
    };

    const int t = blockIdx.x * blockDim.x + tid;
    const int nthr = gridDim.x * blockDim.x;
    const int E4 = E >> 2;

    // 4 strided groups batched per super-iteration: 20 streaming loads
    // (320 B) in flight per thread to compensate the LDS-capped occupancy.
#define LOADG(s, g) \
    int4 vi##s, vj##s; float4 ra##s, rb##s, rc##s; \
    const bool act##s = (g) < E4; \
    if (act##s) { vi##s = idx_i4[(g)]; vj##s = idx_j4[(g)]; \
        ra##s = r4[3 * (g) + 0]; rb##s = r4[3 * (g) + 1]; rc##s = r4[3 * (g) + 2]; }
#define COMPG(s) if (act##s) edge4(vi##s, vj##s, ra##s, rb##s, rc##s);

    for (int gb = t; gb < E4; gb += 4 * nthr) {
        const int g0 = gb;
        const int g1 = gb + nthr;
        const int g2 = gb + 2 * nthr;
        const int g3 = gb + 3 * nthr;
        LOADG(0, g0) LOADG(1, g1) LOADG(2, g2) LOADG(3, g3)
        COMPG(0) COMPG(1) COMPG(2) COMPG(3)
    }
#undef LOADG
#undef COMPG

    // tail (E % 4 != 0 — not hit for this benchmark but kept for generality)
    for (int e = (E4 << 2) + t; e < E; e += nthr) {
        const float x  = r_ij[3 * e + 0];
        const float yy = r_ij[3 * e + 1];
        const float zz = r_ij[3 * e + 2];
        edge1(idx_i[e], idx_j[e], x * x + yy * yy + zz * zz);
    }
}

// ===========================================================================
// Fallback (N > ZS_CAP): gather Z/idx_m directly, pow per edge, LDS bins
// ===========================================================================
__global__ __launch_bounds__(256) void zbl_edge_kernel_nows(
    const float* __restrict__ r_ij,
    const int* __restrict__ idx_i,
    const int* __restrict__ idx_j,
    const float* __restrict__ Z,
    const int* __restrict__ idx_m,
    const float* __restrict__ adiv,
    const float* __restrict__ apow,
    const float* __restrict__ a_vector,
    const float* __restrict__ c_vector,
    float* __restrict__ y, int E)
{
    __shared__ float bins[NUM_MOL];
    for (int b = threadIdx.x; b < NUM_MOL; b += blockDim.x) bins[b] = 0.0f;
    __syncthreads();

    const float sp_apow = softplus_f(apow[0]);
    const float sp_adiv = softplus_f(adiv[0]);
    const float sa0 = softplus_f(a_vector[0]);
    const float sa1 = softplus_f(a_vector[1]);
    const float sa2 = softplus_f(a_vector[2]);
    const float sa3 = softplus_f(a_vector[3]);
    float c0 = softplus_f(c_vector[0]);
    float c1 = softplus_f(c_vector[1]);
    float c2 = softplus_f(c_vector[2]);
    float c3 = softplus_f(c_vector[3]);
    const float cs = fabsf(c0) + fabsf(c1) + fabsf(c2) + fabsf(c3);
    const float cinv = 1.0f / cs;
    c0 *= cinv; c1 *= cinv; c2 *= cinv; c3 *= cinv;

    const int stride = gridDim.x * blockDim.x;
    for (int e = blockIdx.x * blockDim.x + threadIdx.x; e < E; e += stride) {
        const int i = idx_i[e];
        const int j = idx_j[e];
        const float zi = Z[i];
        const float zj = Z[j];
        const float x  = r_ij[3 * e + 0];
        const float yy = r_ij[3 * e + 1];
        const float zz = r_ij[3 * e + 2];
        const float d = sqrtf(x * x + yy * yy + zz * zz);

        const float u = d * (1.0f / RCUT);
        const float u3 = u * u * u;
        float fc = 1.0f + u3 * (-10.0f + u * (15.0f - 6.0f * u));
        fc = (d < RCUT) ? fc : 0.0f;

        const float a = (__powf(zi, sp_apow) + __powf(zj, sp_apow)) * sp_adiv;
        const float ad = a * d;
        const float ft = c0 * __expf(-sa0 * ad) + c1 * __expf(-sa1 * ad)
                       + c2 * __expf(-sa2 * ad) + c3 * __expf(-sa3 * ad);

        const float ee = KEHALF * ft * fc * zi * zj / d;
        if (ee != 0.0f) atomicAdd(&bins[idx_m[i]], ee);
    }

    __syncthreads();
    for (int b = threadIdx.x; b < NUM_MOL; b += blockDim.x) {
        const float v = bins[b];
        if (v != 0.0f) atomicAdd(&y[b], v);
    }
}

extern "C" void kernel_launch(void* const* d_in, const int* in_sizes, int n_in,
                              void* d_out, int out_size, void* d_ws, size_t ws_size,
                              hipStream_t stream) {
    // setup_inputs order: Z, r_ij, idx_i, idx_j, idx_m, adiv, apow, a_vector, c_vector
    const float* Z        = (const float*)d_in[0];
    const float* r_ij     = (const float*)d_in[1];
    const int*   idx_i    = (const int*)d_in[2];
    const int*   idx_j    = (const int*)d_in[3];
    const int*   idx_m    = (const int*)d_in[4];
    const float* adiv     = (const float*)d_in[5];
    const float* apow     = (const float*)d_in[6];
    const float* a_vector = (const float*)d_in[7];
    const float* c_vector = (const float*)d_in[8];
    float* y = (float*)d_out;

    const int N = in_sizes[0];
    const int E = in_sizes[1] / 3;

    // d_out is poisoned 0xAA before every launch -> zero it (graph-safe memset node)
    hipMemsetAsync(y, 0, (size_t)out_size * sizeof(float), stream);

    if (N <= ZS_CAP) {
        // single kernel, no workspace: 256 blocks x 1024 threads,
        // 1 block/CU (128 KiB LDS), 16 waves/CU
        zbl_edge_lds<<<256, 1024, 0, stream>>>(
            (const float4*)r_ij, (const int4*)idx_i, (const int4*)idx_j,
            idx_i, idx_j, r_ij, Z, idx_m, adiv, apow, a_vector, c_vector,
            y, N, E);
    } else {
        zbl_edge_kernel_nows<<<2048, 256, 0, stream>>>(r_ij, idx_i, idx_j, Z, idx_m,
                                                       adiv, apow, a_vector, c_vector, y, E);
    }
}

// Round 5
// 124.050 us; speedup vs baseline: 1.0371x; 1.0371x over previous
//
#include <hip/hip_runtime.h>

#define NUM_MOL 1024
#define KEHALF 7.199822675975274f
#define RCUT 10.0f
// u8 z-table capacity in LDS; + 256-float LUT = 128 KiB static LDS
#define ZS_CAP 130048

__device__ __forceinline__ float softplus_f(float x) {
    // log1p(exp(x)); fast path (params are O(1), tolerance allows ~1e-7 rel)
    return (x > 20.0f) ? x : __logf(1.0f + __expf(x));
}

__device__ __forceinline__ float uni(float x) {
    // force uniform value into an SGPR (frees VGPRs, marks uniformity)
    return __int_as_float(__builtin_amdgcn_readfirstlane(__float_as_int(x)));
}

// ===========================================================================
// Prep: Z (f32) -> u8 table in workspace, once per launch.
// Turns each block's 400KB f32 broadcast-read + convert into a 100KB memcpy:
// aggregate LDS-fill traffic 100MB -> 25MB, fill VALU ~0.
// ===========================================================================
__global__ __launch_bounds__(256) void zbl_prep_u8(
    const float* __restrict__ Z, unsigned char* __restrict__ zu8, int N)
{
    const int n4 = blockIdx.x * blockDim.x + threadIdx.x;   // one float4 per thread
    const int nv4 = N >> 2;
    if (n4 < nv4) {
        const float4 zv = ((const float4*)Z)[n4];
        uchar4 pk;
        pk.x = (unsigned char)(int)zv.x;
        pk.y = (unsigned char)(int)zv.y;
        pk.z = (unsigned char)(int)zv.z;
        pk.w = (unsigned char)(int)zv.w;
        ((uchar4*)zu8)[n4] = pk;
    }
    // scalar tail
    const int base = nv4 << 2;
    const int r = base + n4;
    if (n4 < N - base) zu8[r] = (unsigned char)(int)Z[r];
}

// ===========================================================================
// Primary path:
//   - u8 z per atom in LDS (100 KB, raw copy from prep'd table),
//     z^softplus(apow) via 256-entry LDS LUT. Edge lookups = DS pipe only.
//   - exact early-out: exp underflows to 0 for ~99% of edges; survivors
//     lazily gather idx_m[i] (masked load) and atomicAdd into y[mol].
// ===========================================================================

struct SmemT {
    float zptab[256];          // z^softplus(apow), z in [0,255]
    unsigned char zs[ZS_CAP];  // per-atom z
};

template <bool FAST_FILL>
__global__ __launch_bounds__(1024, 4) void zbl_edge_lds(
    const float4* __restrict__ r4,
    const int4* __restrict__ idx_i4,
    const int4* __restrict__ idx_j4,
    const int* __restrict__ idx_i,
    const int* __restrict__ idx_j,
    const float* __restrict__ r_ij,
    const float* __restrict__ Z,
    const unsigned char* __restrict__ zu8,   // prep'd table (FAST_FILL)
    const int* __restrict__ idx_m,
    const float* __restrict__ adiv,
    const float* __restrict__ apow,
    const float* __restrict__ a_vector,
    const float* __restrict__ c_vector,
    float* __restrict__ y, int N, int E)
{
    __shared__ SmemT sm;
    const int tid = threadIdx.x;

    // ---- fill LDS z-table ----
    if (FAST_FILL) {
        // raw 16B-chunk copy of the prep'd u8 table (zs is 16B-aligned:
        // zptab is 1024B). Reads past N up to chunk end are in-bounds of
        // the 256MiB workspace and never indexed.
        const uint4* src = (const uint4*)zu8;
        uint4* dst = (uint4*)sm.zs;
        const int nchunk = (N + 15) >> 4;
        for (int k = tid; k < nchunk; k += blockDim.x) dst[k] = src[k];
    } else {
        const int nv4 = N >> 2;
        const float4* Z4 = (const float4*)Z;
        uchar4* dst = (uchar4*)sm.zs;
        for (int k = tid; k < nv4; k += blockDim.x) {
            const float4 zv = Z4[k];
            uchar4 pk;
            pk.x = (unsigned char)(int)zv.x;
            pk.y = (unsigned char)(int)zv.y;
            pk.z = (unsigned char)(int)zv.z;
            pk.w = (unsigned char)(int)zv.w;
            dst[k] = pk;
        }
        for (int k = (nv4 << 2) + tid; k < N; k += blockDim.x)
            sm.zs[k] = (unsigned char)(int)Z[k];
    }
    if (tid < 256) {
        const float p = softplus_f(apow[0]);
        sm.zptab[tid] = (tid > 0) ? __powf((float)tid, p) : 0.0f;
    }

    // ---- uniform scalar parameters -> SGPRs ----
    const float sp_adiv = uni(softplus_f(adiv[0]));
    const float sa0 = uni(softplus_f(a_vector[0]));
    const float sa1 = uni(softplus_f(a_vector[1]));
    const float sa2 = uni(softplus_f(a_vector[2]));
    const float sa3 = uni(softplus_f(a_vector[3]));
    float c0 = softplus_f(c_vector[0]);
    float c1 = softplus_f(c_vector[1]);
    float c2 = softplus_f(c_vector[2]);
    float c3 = softplus_f(c_vector[3]);
    const float cinv = 1.0f / (fabsf(c0) + fabsf(c1) + fabsf(c2) + fabsf(c3));
    const float k0 = uni(c0 * cinv);
    const float k1 = uni(c1 * cinv);
    const float k2 = uni(c2 * cinv);
    const float k3 = uni(c3 * cinv);
    const float samin = fminf(fminf(sa0, sa1), fminf(sa2, sa3));
    // survivor predicate: (zpi+zpj)*d < C2  <=>  min-exponent arg < 104
    const float C2 = uni(104.0f / (sp_adiv * samin));

    __syncthreads();

    auto edge1 = [&](int i, int j, float d2) {
        const int zi = sm.zs[i];                 // ds_read_u8 (random, cheap)
        const int zj = sm.zs[j];
        const float zpi = sm.zptab[zi];          // ds_read_b32 (256-word LUT)
        const float zpj = sm.zptab[zj];
        const float d = sqrtf(d2);
        const float zsum = zpi + zpj;
        // exact early-out: if zsum*d >= C2, every expf flushes to 0.0f
        // -> ft == 0 -> ee == 0. Survivors (~1%): masked idx_m gather +
        // direct global atomic.
        if (zsum * d < C2) {
            const float rinv = rsqrtf(d2);
            const float u = d * (1.0f / RCUT);
            const float u3 = u * u * u;
            float fc = 1.0f + u3 * (-10.0f + u * (15.0f - 6.0f * u));
            fc = (d < RCUT) ? fc : 0.0f;
            const float ad = zsum * sp_adiv * d;
            const float ft = k0 * __expf(-sa0 * ad) + k1 * __expf(-sa1 * ad)
                           + k2 * __expf(-sa2 * ad) + k3 * __expf(-sa3 * ad);
            const float ee = KEHALF * ft * fc * (float)(zi * zj) * rinv;
            if (ee != 0.0f) atomicAdd(&y[idx_m[i]], ee);
        }
    };
    auto edge4 = [&](const int4& vi, const int4& vj,
                     const float4& r0, const float4& r1, const float4& r2) {
        edge1(vi.x, vj.x, r0.x * r0.x + r0.y * r0.y + r0.z * r0.z);
        edge1(vi.y, vj.y, r0.w * r0.w + r1.x * r1.x + r1.y * r1.y);
        edge1(vi.z, vj.z, r1.z * r1.z + r1.w * r1.w + r2.x * r2.x);
        edge1(vi.w, vj.w, r2.y * r2.y + r2.z * r2.z + r2.w * r2.w);
    };

    const int t = blockIdx.x * blockDim.x + tid;
    const int nthr = gridDim.x * blockDim.x;
    const int E4 = E >> 2;

    // 4 strided groups batched per super-iteration: 20 streaming loads
    // (320 B) in flight per thread to compensate the LDS-capped occupancy.
#define LOADG(s, g) \
    int4 vi##s, vj##s; float4 ra##s, rb##s, rc##s; \
    const bool act##s = (g) < E4; \
    if (act##s) { vi##s = idx_i4[(g)]; vj##s = idx_j4[(g)]; \
        ra##s = r4[3 * (g) + 0]; rb##s = r4[3 * (g) + 1]; rc##s = r4[3 * (g) + 2]; }
#define COMPG(s) if (act##s) edge4(vi##s, vj##s, ra##s, rb##s, rc##s);

    for (int gb = t; gb < E4; gb += 4 * nthr) {
        const int g0 = gb;
        const int g1 = gb + nthr;
        const int g2 = gb + 2 * nthr;
        const int g3 = gb + 3 * nthr;
        LOADG(0, g0) LOADG(1, g1) LOADG(2, g2) LOADG(3, g3)
        COMPG(0) COMPG(1) COMPG(2) COMPG(3)
    }
#undef LOADG
#undef COMPG

    // tail (E % 4 != 0 — not hit for this benchmark but kept for generality)
    for (int e = (E4 << 2) + t; e < E; e += nthr) {
        const float x  = r_ij[3 * e + 0];
        const float yy = r_ij[3 * e + 1];
        const float zz = r_ij[3 * e + 2];
        edge1(idx_i[e], idx_j[e], x * x + yy * yy + zz * zz);
    }
}

// ===========================================================================
// Fallback (N > ZS_CAP): gather Z/idx_m directly, pow per edge, LDS bins
// ===========================================================================
__global__ __launch_bounds__(256) void zbl_edge_kernel_nows(
    const float* __restrict__ r_ij,
    const int* __restrict__ idx_i,
    const int* __restrict__ idx_j,
    const float* __restrict__ Z,
    const int* __restrict__ idx_m,
    const float* __restrict__ adiv,
    const float* __restrict__ apow,
    const float* __restrict__ a_vector,
    const float* __restrict__ c_vector,
    float* __restrict__ y, int E)
{
    __shared__ float bins[NUM_MOL];
    for (int b = threadIdx.x; b < NUM_MOL; b += blockDim.x) bins[b] = 0.0f;
    __syncthreads();

    const float sp_apow = softplus_f(apow[0]);
    const float sp_adiv = softplus_f(adiv[0]);
    const float sa0 = softplus_f(a_vector[0]);
    const float sa1 = softplus_f(a_vector[1]);
    const float sa2 = softplus_f(a_vector[2]);
    const float sa3 = softplus_f(a_vector[3]);
    float c0 = softplus_f(c_vector[0]);
    float c1 = softplus_f(c_vector[1]);
    float c2 = softplus_f(c_vector[2]);
    float c3 = softplus_f(c_vector[3]);
    const float cs = fabsf(c0) + fabsf(c1) + fabsf(c2) + fabsf(c3);
    const float cinv = 1.0f / cs;
    c0 *= cinv; c1 *= cinv; c2 *= cinv; c3 *= cinv;

    const int stride = gridDim.x * blockDim.x;
    for (int e = blockIdx.x * blockDim.x + threadIdx.x; e < E; e += stride) {
        const int i = idx_i[e];
        const int j = idx_j[e];
        const float zi = Z[i];
        const float zj = Z[j];
        const float x  = r_ij[3 * e + 0];
        const float yy = r_ij[3 * e + 1];
        const float zz = r_ij[3 * e + 2];
        const float d = sqrtf(x * x + yy * yy + zz * zz);

        const float u = d * (1.0f / RCUT);
        const float u3 = u * u * u;
        float fc = 1.0f + u3 * (-10.0f + u * (15.0f - 6.0f * u));
        fc = (d < RCUT) ? fc : 0.0f;

        const float a = (__powf(zi, sp_apow) + __powf(zj, sp_apow)) * sp_adiv;
        const float ad = a * d;
        const float ft = c0 * __expf(-sa0 * ad) + c1 * __expf(-sa1 * ad)
                       + c2 * __expf(-sa2 * ad) + c3 * __expf(-sa3 * ad);

        const float ee = KEHALF * ft * fc * zi * zj / d;
        if (ee != 0.0f) atomicAdd(&bins[idx_m[i]], ee);
    }

    __syncthreads();
    for (int b = threadIdx.x; b < NUM_MOL; b += blockDim.x) {
        const float v = bins[b];
        if (v != 0.0f) atomicAdd(&y[b], v);
    }
}

extern "C" void kernel_launch(void* const* d_in, const int* in_sizes, int n_in,
                              void* d_out, int out_size, void* d_ws, size_t ws_size,
                              hipStream_t stream) {
    // setup_inputs order: Z, r_ij, idx_i, idx_j, idx_m, adiv, apow, a_vector, c_vector
    const float* Z        = (const float*)d_in[0];
    const float* r_ij     = (const float*)d_in[1];
    const int*   idx_i    = (const int*)d_in[2];
    const int*   idx_j    = (const int*)d_in[3];
    const int*   idx_m    = (const int*)d_in[4];
    const float* adiv     = (const float*)d_in[5];
    const float* apow     = (const float*)d_in[6];
    const float* a_vector = (const float*)d_in[7];
    const float* c_vector = (const float*)d_in[8];
    float* y = (float*)d_out;

    const int N = in_sizes[0];
    const int E = in_sizes[1] / 3;

    // d_out is poisoned 0xAA before every launch -> zero it (graph-safe memset node)
    hipMemsetAsync(y, 0, (size_t)out_size * sizeof(float), stream);

    if (N <= ZS_CAP) {
        if (ws_size >= (size_t)N + 16) {
            unsigned char* zu8 = (unsigned char*)d_ws;
            zbl_prep_u8<<<(N / 4 + 255) / 256 + 1, 256, 0, stream>>>(Z, zu8, N);
            zbl_edge_lds<true><<<256, 1024, 0, stream>>>(
                (const float4*)r_ij, (const int4*)idx_i, (const int4*)idx_j,
                idx_i, idx_j, r_ij, Z, zu8, idx_m, adiv, apow, a_vector, c_vector,
                y, N, E);
        } else {
            zbl_edge_lds<false><<<256, 1024, 0, stream>>>(
                (const float4*)r_ij, (const int4*)idx_i, (const int4*)idx_j,
                idx_i, idx_j, r_ij, Z, (const unsigned char*)nullptr, idx_m,
                adiv, apow, a_vector, c_vector, y, N, E);
        }
    } else {
        zbl_edge_kernel_nows<<<2048, 256, 0, stream>>>(r_ij, idx_i, idx_j, Z, idx_m,
                                                       adiv, apow, a_vector, c_vector, y, E);
    }
}